// Round 6
// baseline (1235.219 us; speedup 1.0000x reference)
//
#include <hip/hip_runtime.h>
#include <cmath>

#define NROWS 65536
#define EDIM  1024
#define KST   4

// ---- pre-kernel: transpose W_inv (4,1024,5) -> WiT (4,5,1024) in d_ws ----
__global__ __launch_bounds__(256) void winv_transpose(const float* __restrict__ W_inv,
                                                      float* __restrict__ WiT) {
    const int t = blockIdx.x * 256 + threadIdx.x;   // 4096 threads total
    const int i = t >> 10;                          // stage
    const int e = t & 1023;
    const float* src = W_inv + (size_t)i * 5120 + (size_t)e * 5;
    const float w0 = src[0], w1 = src[1], w2 = src[2], w3 = src[3], w4 = src[4];
    float* dst = WiT + (size_t)i * 5120 + e;
    dst[0]    = w0;
    dst[1024] = w1;
    dst[2048] = w2;
    dst[3072] = w3;
    dst[4096] = w4;
}

// Wave-64 sum reduction, pure VALU (DPP) — LLVM atomic-optimizer sequence.
// Result valid in lane 63; NO LDS-pipe (ds_swizzle) ops, unlike __shfl_xor.
__device__ __forceinline__ float dpp_sum(float x) {
    float t;
    t = __int_as_float(__builtin_amdgcn_update_dpp(0, __float_as_int(x), 0x111, 0xf, 0xf, false)); x += t; // row_shr:1
    t = __int_as_float(__builtin_amdgcn_update_dpp(0, __float_as_int(x), 0x112, 0xf, 0xf, false)); x += t; // row_shr:2
    t = __int_as_float(__builtin_amdgcn_update_dpp(0, __float_as_int(x), 0x114, 0xf, 0xf, false)); x += t; // row_shr:4
    t = __int_as_float(__builtin_amdgcn_update_dpp(0, __float_as_int(x), 0x118, 0xf, 0xf, false)); x += t; // row_shr:8
    t = __int_as_float(__builtin_amdgcn_update_dpp(0, __float_as_int(x), 0x142, 0xa, 0xf, false)); x += t; // row_bcast:15
    t = __int_as_float(__builtin_amdgcn_update_dpp(0, __float_as_int(x), 0x143, 0xc, 0xf, false)); x += t; // row_bcast:31
    return x;
}
__device__ __forceinline__ float lane63(float x) {
    return __int_as_float(__builtin_amdgcn_readlane(__float_as_int(x), 63));
}

// LDS (floats): [s*5120 + d*1024 + e)          Wp, stages 0..3   (80 KB)
//               [20480 + s*5120 + d*1024 + e)  WiT, stages 0..3  (80 KB)
// 1024-thr block (16 waves) * 4 rows/wave = 64 rows/block; weights staged ONCE;
// single barrier; all reductions on the VALU pipe (DPP), not LDS swizzles.
__global__ __launch_bounds__(1024, 4) void rvq_fused(
    const float* __restrict__ h_in,    // (N,1024)
    const float* __restrict__ W_proj,  // (4,5,1024)
    const float* __restrict__ b_proj,  // (4,5)
    const float* __restrict__ WiT,     // (4,5,1024) transposed W_inv
    const float* __restrict__ b_inv,   // (4,1024)
    const float* __restrict__ temp,    // (1)
    const float* __restrict__ u,       // (4,N,5,8)
    const float* __restrict__ p,       // (N)
    float* __restrict__ out_q,         // (N,1024)
    float* __restrict__ out_code,      // (N,20)
    float* __restrict__ out_loss,      // (1)
    float shift012, float shift3)
{
    __shared__ float sW[40960];   // 163840 bytes exactly

    const int tid  = threadIdx.x;
    const int lane = tid & 63;
    const int wib  = tid >> 6;                  // 0..15
    const int wid  = blockIdx.x * 16 + wib;
    const int row0 = wid * 4;                   // 4 rows per wave

    // ---- lane-role constants (d,c) grid; lanes 40..63 duplicate d=4 ----
    int dl = lane >> 3; if (dl > 4) dl = 4;
    const int   cl     = lane & 7;
    const float stepf  = (float)(cl - 4);
    const bool  valid  = (dl < 3) || (dl == 3 && cl >= 1 && cl <= 6)
                                  || (dl == 4 && cl >= 2 && cl <= 6);
    const float shiftd = (dl < 3) ? shift012 : ((dl == 3) ? shift3 : 0.0f);
    const float halfld = (dl < 3) ? 3.4965f : ((dl == 3) ? 2.4975f : 1.998f);
    const float offd   = (dl == 4) ? 0.0f : 0.5f;
    const float invhwd = (dl < 3) ? 0.25f : ((dl == 3) ? (1.0f/3.0f) : 0.5f);
    const int   ulane  = (lane < 40) ? lane : 39;

    const float tval = temp[0];
    const float te = fmaxf(tval * tval, 1e-8f);       // temp_eff
    const float inv_te  = 1.0f / te;                  // == alpha
    const float alpham1 = inv_te - 1.0f;

    // ---- load rows (e = 4*lane + 256*j) + p ----
    float4 r4[4][4];
    float  p_r[4];
    float  ss[4];
    #pragma unroll
    for (int rr = 0; rr < 4; ++rr) {
        const float4* src = (const float4*)(h_in + (size_t)(row0 + rr) * EDIM);
        #pragma unroll
        for (int j = 0; j < 4; ++j) r4[rr][j] = src[lane + 64 * j];
        p_r[rr] = p[row0 + rr];
    }

    // ---- stage ALL weights once: 10 coalesced float4 copies per thread ----
    {
        const float4* gp = (const float4*)W_proj;
        float4* sp = (float4*)sW;
        #pragma unroll
        for (int k = 0; k < 5; ++k) sp[tid + k * 1024] = gp[tid + k * 1024];
        const float4* gw = (const float4*)WiT;
        float4* sw2 = (float4*)(sW + 20480);
        #pragma unroll
        for (int k = 0; k < 5; ++k) sw2[tid + k * 1024] = gw[tid + k * 1024];
    }

    #pragma unroll
    for (int rr = 0; rr < 4; ++rr) {
        float s = 0.f;
        #pragma unroll
        for (int j = 0; j < 4; ++j) {
            s = fmaf(r4[rr][j].x, r4[rr][j].x, s);
            s = fmaf(r4[rr][j].y, r4[rr][j].y, s);
            s = fmaf(r4[rr][j].z, r4[rr][j].z, s);
            s = fmaf(r4[rr][j].w, r4[rr][j].w, s);
        }
        ss[rr] = (p_r[rr] <= 0.0f) ? s : 0.0f;   // p==0 edge: q_mix=0 -> ||h_in||
    }

    __syncthreads();   // the ONLY barrier before the epilogue

    #pragma unroll
    for (int i = 0; i < KST; ++i) {
        const int wb  = i * 5120;           // Wp stage base
        const int wbi = 20480 + i * 5120;   // WiT stage base

        // gumbel uniforms for this stage — issue early, consumed ~300 inst later
        float uu[4];
        #pragma unroll
        for (int rr = 0; rr < 4; ++rr)
            uu[rr] = u[(size_t)i * 2621440 + (size_t)(row0 + rr) * 40 + ulane];
        // b_proj biases (uniform scalar loads)
        float bp[5];
        #pragma unroll
        for (int d = 0; d < 5; ++d) bp[d] = b_proj[i * 5 + d];

        // ---- proj: h[d] = sum_e Wp[d][e] * r[e]  (identical in-lane FMA order) ----
        float acc[5][4];
        #pragma unroll
        for (int d = 0; d < 5; ++d)
            #pragma unroll
            for (int rr = 0; rr < 4; ++rr) acc[d][rr] = 0.f;

        #pragma unroll
        for (int d = 0; d < 5; ++d) {
            #pragma unroll
            for (int j = 0; j < 4; ++j) {
                const float4 w = *(const float4*)&sW[wb + d * 1024 + 4 * lane + 256 * j];
                #pragma unroll
                for (int rr = 0; rr < 4; ++rr) {
                    float a = acc[d][rr];
                    a = fmaf(w.x, r4[rr][j].x, a);
                    a = fmaf(w.y, r4[rr][j].y, a);
                    a = fmaf(w.z, r4[rr][j].z, a);
                    a = fmaf(w.w, r4[rr][j].w, a);
                    acc[d][rr] = a;
                }
            }
        }
        // ---- cross-lane reduce on the VALU pipe (DPP), + bp as uniform add ----
        // hd[d][rr] is wave-uniform (readlane 63 -> broadcast via SGPR)
        float hd[5][4];
        #pragma unroll
        for (int d = 0; d < 5; ++d)
            #pragma unroll
            for (int rr = 0; rr < 4; ++rr)
                hd[d][rr] = lane63(dpp_sum(acc[d][rr])) + bp[d];

        // ---- bound + gumbel-argmax (identical math/order; shfl only xor 1/2/4) ----
        float zq_mine[4];
        #pragma unroll
        for (int rr = 0; rr < 4; ++rr) {
            float hsel = hd[0][rr];
            hsel = (dl == 1) ? hd[1][rr] : hsel;
            hsel = (dl == 2) ? hd[2][rr] : hsel;
            hsel = (dl == 3) ? hd[3][rr] : hsel;
            hsel = (dl == 4) ? hd[4][rr] : hsel;
            const float z  = __fsub_rn(__fmul_rn(tanhf(hsel + shiftd), halfld), offd);
            const float g1 = logf(uu[rr] + 1e-20f);
            const float g  = -logf(-g1 + 1e-20f);
            const float df = __fsub_rn(z, stepf);
            float d2 = __fmul_rn(df, df);
            d2 = valid ? d2 : 1e8f;
            const float d2x = fmaf(alpham1, d2, d2);
            float y   = -(d2x * inv_te) + g;
            int   idx = cl;
            #pragma unroll
            for (int m = 1; m <= 4; m <<= 1) {     // argmax in 8-lane group
                const float yo = __shfl_xor(y, m);
                const int   io = __shfl_xor(idx, m);
                const bool take = (yo > y) || (yo == y && io < idx);
                y   = take ? yo : y;
                idx = take ? io : idx;
            }
            zq_mine[rr] = (float)(idx - 4) * invhwd;
        }
        if (lane < 40 && cl == 0) {
            #pragma unroll
            for (int rr = 0; rr < 4; ++rr)
                out_code[(size_t)(row0 + rr) * 20 + i * 5 + dl] = zq_mine[rr];
        }

        // broadcast zq[d][rr] into SGPRs (readlane, imm lane)
        float zq[5][4];
        #pragma unroll
        for (int d = 0; d < 5; ++d)
            #pragma unroll
            for (int rr = 0; rr < 4; ++rr)
                zq[d][rr] = __int_as_float(
                    __builtin_amdgcn_readlane(__float_as_int(zq_mine[rr]), d * 8));

        // ---- inverse proj fused into r update (identical rounding order):
        //      t = b_inv + zq0*w0 + ... + zq4*w4 ; r -= t ----
        const float4* bvp = (const float4*)(b_inv + (size_t)i * EDIM);
        #pragma unroll
        for (int j = 0; j < 4; ++j) {
            const int eo = 4 * lane + 256 * j;
            const float4 b  = bvp[lane + 64 * j];   // L1-hot (all waves same lines)
            const float4 w0 = *(const float4*)&sW[wbi + eo];
            const float4 w1 = *(const float4*)&sW[wbi + 1024 + eo];
            const float4 w2 = *(const float4*)&sW[wbi + 2048 + eo];
            const float4 w3 = *(const float4*)&sW[wbi + 3072 + eo];
            const float4 w4 = *(const float4*)&sW[wbi + 4096 + eo];
            #pragma unroll
            for (int rr = 0; rr < 4; ++rr) {
                float tx = b.x, ty = b.y, tz = b.z, tw = b.w;
                tx = fmaf(zq[0][rr], w0.x, tx); ty = fmaf(zq[0][rr], w0.y, ty);
                tz = fmaf(zq[0][rr], w0.z, tz); tw = fmaf(zq[0][rr], w0.w, tw);
                tx = fmaf(zq[1][rr], w1.x, tx); ty = fmaf(zq[1][rr], w1.y, ty);
                tz = fmaf(zq[1][rr], w1.z, tz); tw = fmaf(zq[1][rr], w1.w, tw);
                tx = fmaf(zq[2][rr], w2.x, tx); ty = fmaf(zq[2][rr], w2.y, ty);
                tz = fmaf(zq[2][rr], w2.z, tz); tw = fmaf(zq[2][rr], w2.w, tw);
                tx = fmaf(zq[3][rr], w3.x, tx); ty = fmaf(zq[3][rr], w3.y, ty);
                tz = fmaf(zq[3][rr], w3.z, tz); tw = fmaf(zq[3][rr], w3.w, tw);
                tx = fmaf(zq[4][rr], w4.x, tx); ty = fmaf(zq[4][rr], w4.y, ty);
                tz = fmaf(zq[4][rr], w4.z, tz); tw = fmaf(zq[4][rr], w4.w, tw);
                r4[rr][j].x -= tx; r4[rr][j].y -= ty;
                r4[rr][j].z -= tz; r4[rr][j].w -= tw;
            }
        }

        // ---- loss snapshot: ||r||^2 at the selected stage ----
        const float lo = i * 0.25f, hi = (i + 1) * 0.25f;
        #pragma unroll
        for (int rr = 0; rr < 4; ++rr) {
            if (lo < p_r[rr] && p_r[rr] <= hi) {
                float s = 0.f;
                #pragma unroll
                for (int j = 0; j < 4; ++j) {
                    s = fmaf(r4[rr][j].x, r4[rr][j].x, s);
                    s = fmaf(r4[rr][j].y, r4[rr][j].y, s);
                    s = fmaf(r4[rr][j].z, r4[rr][j].z, s);
                    s = fmaf(r4[rr][j].w, r4[rr][j].w, s);
                }
                ss[rr] = s;
            }
        }
    }

    // ---- epilogue: out_q = h_in - r_final; loss reduce (reuse sW) ----
    float lsum = 0.f;
    #pragma unroll
    for (int rr = 0; rr < 4; ++rr) {
        float v = ss[rr];
        v += __shfl_xor(v, 1);
        v += __shfl_xor(v, 2);
        v += __shfl_xor(v, 4);
        v += __shfl_xor(v, 8);
        v += __shfl_xor(v, 16);
        v += __shfl_xor(v, 32);
        lsum += sqrtf(v);
    }
    #pragma unroll
    for (int rr = 0; rr < 4; ++rr) {
        const float4* src = (const float4*)(h_in + (size_t)(row0 + rr) * EDIM);
        float4* dst = (float4*)(out_q + (size_t)(row0 + rr) * EDIM);
        #pragma unroll
        for (int j = 0; j < 4; ++j) {
            const float4 h = src[lane + 64 * j];
            float4 o;
            o.x = h.x - r4[rr][j].x;
            o.y = h.y - r4[rr][j].y;
            o.z = h.z - r4[rr][j].z;
            o.w = h.w - r4[rr][j].w;
            dst[lane + 64 * j] = o;
        }
    }
    __syncthreads();                       // all weight reads done -> sW reusable
    if (lane == 0) sW[wib] = lsum;
    __syncthreads();
    if (tid == 0) {
        float bl = 0.f;
        #pragma unroll
        for (int k = 0; k < 16; ++k) bl += sW[k];
        atomicAdd(out_loss, bl * (1.0f / 65536.0f));
    }
}

extern "C" void kernel_launch(void* const* d_in, const int* in_sizes, int n_in,
                              void* d_out, int out_size, void* d_ws, size_t ws_size,
                              hipStream_t stream) {
    (void)in_sizes; (void)n_in; (void)out_size; (void)ws_size;
    const float* h_in   = (const float*)d_in[0];
    const float* W_proj = (const float*)d_in[1];
    const float* b_proj = (const float*)d_in[2];
    const float* W_inv  = (const float*)d_in[3];
    const float* b_inv  = (const float*)d_in[4];
    const float* temp   = (const float*)d_in[5];
    const float* u      = (const float*)d_in[6];
    const float* p      = (const float*)d_in[7];

    float* out_q    = (float*)d_out;
    float* out_code = out_q + (size_t)NROWS * EDIM;
    float* out_loss = out_code + (size_t)NROWS * 20;

    float* WiT = (float*)d_ws;   // 4*5*1024 floats = 80 KB scratch

    // loss accumulator must start at 0 (d_out is poisoned before every call)
    hipMemsetAsync(out_loss, 0, sizeof(float), stream);

    // transpose W_inv once per call (80 KB, ~2 us)
    hipLaunchKernelGGL(winv_transpose, dim3(16), dim3(256), 0, stream, W_inv, WiT);

    // shift constants computed exactly as numpy does (f64 then cast)
    double hl01 = (8.0 - 1.0) * (1.0 - 1e-3) / 2.0;   // 3.4965
    double hl3  = (6.0 - 1.0) * (1.0 - 1e-3) / 2.0;   // 2.4975
    float shift012 = (float)std::tan(0.5 / hl01);
    float shift3   = (float)std::tan(0.5 / hl3);

    dim3 grid(NROWS / 64);   // 16 waves/block * 4 rows/wave
    dim3 block(1024);
    hipLaunchKernelGGL(rvq_fused, grid, block, 0, stream,
                       h_in, W_proj, b_proj, WiT, b_inv, temp, u, p,
                       out_q, out_code, out_loss, shift012, shift3);
}

// Round 8
// 1199.441 us; speedup vs baseline: 1.0298x; 1.0298x over previous
//
#include <hip/hip_runtime.h>
#include <cmath>

#define NROWS 65536
#define EDIM  1024
#define KST   4

// ---- pre-kernel: transpose W_inv (4,1024,5) -> WiT (4,5,1024) in d_ws ----
__global__ __launch_bounds__(256) void winv_transpose(const float* __restrict__ W_inv,
                                                      float* __restrict__ WiT) {
    const int t = blockIdx.x * 256 + threadIdx.x;   // 4096 threads total
    const int i = t >> 10;                          // stage
    const int e = t & 1023;
    const float* src = W_inv + (size_t)i * 5120 + (size_t)e * 5;
    const float w0 = src[0], w1 = src[1], w2 = src[2], w3 = src[3], w4 = src[4];
    float* dst = WiT + (size_t)i * 5120 + e;
    dst[0]    = w0;
    dst[1024] = w1;
    dst[2048] = w2;
    dst[3072] = w3;
    dst[4096] = w4;
}

// LDS (floats): [s*5120 + d*1024 + e)          Wp, stages 0..3   (80 KB)
//               [20480 + s*5120 + d*1024 + e)  WiT, stages 0..3  (80 KB)
// 1024-thr block (16 waves) * 4 rows/wave; weights staged ONCE; one barrier.
// amdgpu_waves_per_eu(4,4): LDS already caps at 4 waves/EU, so pin the
// register allocator to the matching 128-VGPR budget — without this the
// backend targets 8 waves/EU (64 VGPRs) and spills ~2 GB to scratch,
// which R1/R2/R5/R6 counters show is the entire bottleneck
// (phantom hbm_bytes scales with live-set/VGPR; dur == hbm_bytes/3.4TB/s).
__global__ __launch_bounds__(1024)
__attribute__((amdgpu_waves_per_eu(4, 4)))
void rvq_fused(
    const float* __restrict__ h_in,    // (N,1024)
    const float* __restrict__ W_proj,  // (4,5,1024)
    const float* __restrict__ b_proj,  // (4,5)
    const float* __restrict__ WiT,     // (4,5,1024) transposed W_inv
    const float* __restrict__ b_inv,   // (4,1024)
    const float* __restrict__ temp,    // (1)
    const float* __restrict__ u,       // (4,N,5,8)
    const float* __restrict__ p,       // (N)
    float* __restrict__ out_q,         // (N,1024)
    float* __restrict__ out_code,      // (N,20)
    float* __restrict__ out_loss,      // (1)
    float shift012, float shift3)
{
    __shared__ float sW[40960];   // 163840 bytes exactly

    const int tid  = threadIdx.x;
    const int lane = tid & 63;
    const int wib  = tid >> 6;                  // 0..15
    const int wid  = blockIdx.x * 16 + wib;
    const int row0 = wid * 4;                   // 4 rows per wave

    // ---- lane-role constants (d,c) grid; lanes 40..63 duplicate d=4 ----
    int dl = lane >> 3; if (dl > 4) dl = 4;
    const int   cl     = lane & 7;
    const float stepf  = (float)(cl - 4);
    const bool  valid  = (dl < 3) || (dl == 3 && cl >= 1 && cl <= 6)
                                  || (dl == 4 && cl >= 2 && cl <= 6);
    const float shiftd = (dl < 3) ? shift012 : ((dl == 3) ? shift3 : 0.0f);
    const float halfld = (dl < 3) ? 3.4965f : ((dl == 3) ? 2.4975f : 1.998f);
    const float offd   = (dl == 4) ? 0.0f : 0.5f;
    const float invhwd = (dl < 3) ? 0.25f : ((dl == 3) ? (1.0f/3.0f) : 0.5f);
    const int   ulane  = (lane < 40) ? lane : 39;

    const float tval = temp[0];
    const float te = fmaxf(tval * tval, 1e-8f);       // temp_eff
    const float inv_te  = 1.0f / te;                  // == alpha
    const float alpham1 = inv_te - 1.0f;

    // ---- load rows (e = 4*lane + 256*j) + p ----
    float4 r4[4][4];
    float  p_r[4];
    float  ss[4];
    #pragma unroll
    for (int rr = 0; rr < 4; ++rr) {
        const float4* src = (const float4*)(h_in + (size_t)(row0 + rr) * EDIM);
        #pragma unroll
        for (int j = 0; j < 4; ++j) r4[rr][j] = src[lane + 64 * j];
        p_r[rr] = p[row0 + rr];
    }

    // ---- stage ALL weights once: 10 coalesced float4 copies per thread ----
    {
        const float4* gp = (const float4*)W_proj;
        float4* sp = (float4*)sW;
        #pragma unroll
        for (int k = 0; k < 5; ++k) sp[tid + k * 1024] = gp[tid + k * 1024];
        const float4* gw = (const float4*)WiT;
        float4* sw2 = (float4*)(sW + 20480);
        #pragma unroll
        for (int k = 0; k < 5; ++k) sw2[tid + k * 1024] = gw[tid + k * 1024];
    }

    #pragma unroll
    for (int rr = 0; rr < 4; ++rr) {
        float s = 0.f;
        #pragma unroll
        for (int j = 0; j < 4; ++j) {
            s = fmaf(r4[rr][j].x, r4[rr][j].x, s);
            s = fmaf(r4[rr][j].y, r4[rr][j].y, s);
            s = fmaf(r4[rr][j].z, r4[rr][j].z, s);
            s = fmaf(r4[rr][j].w, r4[rr][j].w, s);
        }
        ss[rr] = (p_r[rr] <= 0.0f) ? s : 0.0f;   // p==0 edge: q_mix=0 -> ||h_in||
    }

    __syncthreads();   // the ONLY barrier before the epilogue

    for (int i = 0; i < KST; ++i) {
        const int wb  = i * 5120;           // Wp stage base
        const int wbi = 20480 + i * 5120;   // WiT stage base

        // gumbel uniforms for this stage — issued early, consumed much later
        float uu[4];
        #pragma unroll
        for (int rr = 0; rr < 4; ++rr)
            uu[rr] = u[(size_t)i * 2621440 + (size_t)(row0 + rr) * 40 + ulane];

        // ---- proj: h[d] = sum_e Wp[d][e]*r[e]; butterfly per d right after
        //      its accumulation (identical per-value op order to R1) ----
        float hd[5][4];
        #pragma unroll
        for (int d = 0; d < 5; ++d) {
            const float bp = b_proj[i * 5 + d];
            float a0 = 0.f, a1 = 0.f, a2 = 0.f, a3 = 0.f;
            #pragma unroll
            for (int j = 0; j < 4; ++j) {
                const float4 w = *(const float4*)&sW[wb + d * 1024 + 4 * lane + 256 * j];
                a0 = fmaf(w.x, r4[0][j].x, a0); a0 = fmaf(w.y, r4[0][j].y, a0);
                a0 = fmaf(w.z, r4[0][j].z, a0); a0 = fmaf(w.w, r4[0][j].w, a0);
                a1 = fmaf(w.x, r4[1][j].x, a1); a1 = fmaf(w.y, r4[1][j].y, a1);
                a1 = fmaf(w.z, r4[1][j].z, a1); a1 = fmaf(w.w, r4[1][j].w, a1);
                a2 = fmaf(w.x, r4[2][j].x, a2); a2 = fmaf(w.y, r4[2][j].y, a2);
                a2 = fmaf(w.z, r4[2][j].z, a2); a2 = fmaf(w.w, r4[2][j].w, a2);
                a3 = fmaf(w.x, r4[3][j].x, a3); a3 = fmaf(w.y, r4[3][j].y, a3);
                a3 = fmaf(w.z, r4[3][j].z, a3); a3 = fmaf(w.w, r4[3][j].w, a3);
            }
            float av[4] = {a0, a1, a2, a3};
            #pragma unroll
            for (int rr = 0; rr < 4; ++rr) {
                float v = av[rr];
                v += __shfl_xor(v, 1);
                v += __shfl_xor(v, 2);
                v += __shfl_xor(v, 4);
                v += __shfl_xor(v, 8);
                v += __shfl_xor(v, 16);
                v += __shfl_xor(v, 32);
                hd[d][rr] = v + bp;
            }
        }

        // ---- bound + gumbel-argmax (bit-identical math/order) ----
        float zq_mine[4];
        #pragma unroll
        for (int rr = 0; rr < 4; ++rr) {
            float hsel = hd[0][rr];
            hsel = (dl == 1) ? hd[1][rr] : hsel;
            hsel = (dl == 2) ? hd[2][rr] : hsel;
            hsel = (dl == 3) ? hd[3][rr] : hsel;
            hsel = (dl == 4) ? hd[4][rr] : hsel;
            const float z  = __fsub_rn(__fmul_rn(tanhf(hsel + shiftd), halfld), offd);
            const float g1 = logf(uu[rr] + 1e-20f);
            const float g  = -logf(-g1 + 1e-20f);
            const float df = __fsub_rn(z, stepf);
            float d2 = __fmul_rn(df, df);
            d2 = valid ? d2 : 1e8f;
            const float d2x = fmaf(alpham1, d2, d2);
            float y   = -(d2x * inv_te) + g;
            int   idx = cl;
            #pragma unroll
            for (int m = 1; m <= 4; m <<= 1) {     // argmax in 8-lane group
                const float yo = __shfl_xor(y, m);
                const int   io = __shfl_xor(idx, m);
                const bool take = (yo > y) || (yo == y && io < idx);
                y   = take ? yo : y;
                idx = take ? io : idx;
            }
            zq_mine[rr] = (float)(idx - 4) * invhwd;
        }
        if (lane < 40 && cl == 0) {
            #pragma unroll
            for (int rr = 0; rr < 4; ++rr)
                out_code[(size_t)(row0 + rr) * 20 + i * 5 + dl] = zq_mine[rr];
        }

        // broadcast zq[d][rr] into SGPRs (readlane, imm lane) — no VGPR cost
        float zq[5][4];
        #pragma unroll
        for (int d = 0; d < 5; ++d)
            #pragma unroll
            for (int rr = 0; rr < 4; ++rr)
                zq[d][rr] = __int_as_float(
                    __builtin_amdgcn_readlane(__float_as_int(zq_mine[rr]), d * 8));

        // ---- inverse proj fused into r update (identical rounding order):
        //      t = b_inv + zq0*w0 + ... + zq4*w4 ; r -= t ----
        const float4* bvp = (const float4*)(b_inv + (size_t)i * EDIM);
        #pragma unroll
        for (int j = 0; j < 4; ++j) {
            const int eo = 4 * lane + 256 * j;
            const float4 b  = bvp[lane + 64 * j];   // L1-hot (all waves same lines)
            const float4 w0 = *(const float4*)&sW[wbi + eo];
            const float4 w1 = *(const float4*)&sW[wbi + 1024 + eo];
            const float4 w2 = *(const float4*)&sW[wbi + 2048 + eo];
            const float4 w3 = *(const float4*)&sW[wbi + 3072 + eo];
            const float4 w4 = *(const float4*)&sW[wbi + 4096 + eo];
            #pragma unroll
            for (int rr = 0; rr < 4; ++rr) {
                float tx = b.x, ty = b.y, tz = b.z, tw = b.w;
                tx = fmaf(zq[0][rr], w0.x, tx); ty = fmaf(zq[0][rr], w0.y, ty);
                tz = fmaf(zq[0][rr], w0.z, tz); tw = fmaf(zq[0][rr], w0.w, tw);
                tx = fmaf(zq[1][rr], w1.x, tx); ty = fmaf(zq[1][rr], w1.y, ty);
                tz = fmaf(zq[1][rr], w1.z, tz); tw = fmaf(zq[1][rr], w1.w, tw);
                tx = fmaf(zq[2][rr], w2.x, tx); ty = fmaf(zq[2][rr], w2.y, ty);
                tz = fmaf(zq[2][rr], w2.z, tz); tw = fmaf(zq[2][rr], w2.w, tw);
                tx = fmaf(zq[3][rr], w3.x, tx); ty = fmaf(zq[3][rr], w3.y, ty);
                tz = fmaf(zq[3][rr], w3.z, tz); tw = fmaf(zq[3][rr], w3.w, tw);
                tx = fmaf(zq[4][rr], w4.x, tx); ty = fmaf(zq[4][rr], w4.y, ty);
                tz = fmaf(zq[4][rr], w4.z, tz); tw = fmaf(zq[4][rr], w4.w, tw);
                r4[rr][j].x -= tx; r4[rr][j].y -= ty;
                r4[rr][j].z -= tz; r4[rr][j].w -= tw;
            }
        }

        // ---- loss snapshot: ||r||^2 at the selected stage ----
        const float lo = i * 0.25f, hi = (i + 1) * 0.25f;
        #pragma unroll
        for (int rr = 0; rr < 4; ++rr) {
            if (lo < p_r[rr] && p_r[rr] <= hi) {
                float s = 0.f;
                #pragma unroll
                for (int j = 0; j < 4; ++j) {
                    s = fmaf(r4[rr][j].x, r4[rr][j].x, s);
                    s = fmaf(r4[rr][j].y, r4[rr][j].y, s);
                    s = fmaf(r4[rr][j].z, r4[rr][j].z, s);
                    s = fmaf(r4[rr][j].w, r4[rr][j].w, s);
                }
                ss[rr] = s;
            }
        }
    }

    // ---- epilogue: out_q = h_in - r_final; loss reduce (reuse sW) ----
    float lsum = 0.f;
    #pragma unroll
    for (int rr = 0; rr < 4; ++rr) {
        float v = ss[rr];
        v += __shfl_xor(v, 1);
        v += __shfl_xor(v, 2);
        v += __shfl_xor(v, 4);
        v += __shfl_xor(v, 8);
        v += __shfl_xor(v, 16);
        v += __shfl_xor(v, 32);
        lsum += sqrtf(v);
    }
    #pragma unroll
    for (int rr = 0; rr < 4; ++rr) {
        const float4* src = (const float4*)(h_in + (size_t)(row0 + rr) * EDIM);
        float4* dst = (float4*)(out_q + (size_t)(row0 + rr) * EDIM);
        #pragma unroll
        for (int j = 0; j < 4; ++j) {
            const float4 h = src[lane + 64 * j];
            float4 o;
            o.x = h.x - r4[rr][j].x;
            o.y = h.y - r4[rr][j].y;
            o.z = h.z - r4[rr][j].z;
            o.w = h.w - r4[rr][j].w;
            dst[lane + 64 * j] = o;
        }
    }
    __syncthreads();                       // all weight reads done -> sW reusable
    if (lane == 0) sW[wib] = lsum;
    __syncthreads();
    if (tid == 0) {
        float bl = 0.f;
        #pragma unroll
        for (int k = 0; k < 16; ++k) bl += sW[k];
        atomicAdd(out_loss, bl * (1.0f / 65536.0f));
    }
}

extern "C" void kernel_launch(void* const* d_in, const int* in_sizes, int n_in,
                              void* d_out, int out_size, void* d_ws, size_t ws_size,
                              hipStream_t stream) {
    (void)in_sizes; (void)n_in; (void)out_size; (void)ws_size;
    const float* h_in   = (const float*)d_in[0];
    const float* W_proj = (const float*)d_in[1];
    const float* b_proj = (const float*)d_in[2];
    const float* W_inv  = (const float*)d_in[3];
    const float* b_inv  = (const float*)d_in[4];
    const float* temp   = (const float*)d_in[5];
    const float* u      = (const float*)d_in[6];
    const float* p      = (const float*)d_in[7];

    float* out_q    = (float*)d_out;
    float* out_code = out_q + (size_t)NROWS * EDIM;
    float* out_loss = out_code + (size_t)NROWS * 20;

    float* WiT = (float*)d_ws;   // 4*5*1024 floats = 80 KB scratch

    // loss accumulator must start at 0 (d_out is poisoned before every call)
    hipMemsetAsync(out_loss, 0, sizeof(float), stream);

    // transpose W_inv once per call (80 KB, ~2 us)
    hipLaunchKernelGGL(winv_transpose, dim3(16), dim3(256), 0, stream, W_inv, WiT);

    // shift constants computed exactly as numpy does (f64 then cast)
    double hl01 = (8.0 - 1.0) * (1.0 - 1e-3) / 2.0;   // 3.4965
    double hl3  = (6.0 - 1.0) * (1.0 - 1e-3) / 2.0;   // 2.4975
    float shift012 = (float)std::tan(0.5 / hl01);
    float shift3   = (float)std::tan(0.5 / hl3);

    dim3 grid(NROWS / 64);   // 16 waves/block * 4 rows/wave
    dim3 block(1024);
    hipLaunchKernelGGL(rvq_fused, grid, block, 0, stream,
                       h_in, W_proj, b_proj, WiT, b_inv, temp, u, p,
                       out_q, out_code, out_loss, shift012, shift3);
}

// Round 9
// 676.592 us; speedup vs baseline: 1.8256x; 1.7728x over previous
//
#include <hip/hip_runtime.h>
#include <cmath>

#define NROWS 65536
#define EDIM  1024
#define KST   4

// ---- pre-kernel: transpose W_inv (4,1024,5) -> WiT (4,5,1024) in d_ws ----
__global__ __launch_bounds__(256) void winv_transpose(const float* __restrict__ W_inv,
                                                      float* __restrict__ WiT) {
    const int t = blockIdx.x * 256 + threadIdx.x;   // 4096 threads total
    const int i = t >> 10;                          // stage
    const int e = t & 1023;
    const float* src = W_inv + (size_t)i * 5120 + (size_t)e * 5;
    const float w0 = src[0], w1 = src[1], w2 = src[2], w3 = src[3], w4 = src[4];
    float* dst = WiT + (size_t)i * 5120 + e;
    dst[0]    = w0;
    dst[1024] = w1;
    dst[2048] = w2;
    dst[3072] = w3;
    dst[4096] = w4;
}

// R1 structure (measured best, 589 us): 256-thr block (4 waves), per-stage
// 44 KB LDS restage, butterfly reductions — bit-identical numerics.
// Changes vs R1: 2 rows/wave (live set ~98 regs, was ~135) and
// __launch_bounds__(256,2) (budget 256 regs/wave — the one allocation lever
// that verifiably worked on this toolchain: (256,3) -> 84+84 in R1).
// Goal: eliminate the scratch-spill traffic that R1/R2/R5/R6/R8 counters
// show is the bottleneck (phantom 1.1-1.6 GB HBM; dur == hbm_bytes/3.5TB/s).
// LDS (floats): [0,5120) Wp[d][e]; [5120,10240) WiT[d][e]; [10240,11264) b_inv
__global__ __launch_bounds__(256, 2) void rvq_fused(
    const float* __restrict__ h_in,    // (N,1024)
    const float* __restrict__ W_proj,  // (4,5,1024)
    const float* __restrict__ b_proj,  // (4,5)
    const float* __restrict__ WiT,     // (4,5,1024) transposed W_inv
    const float* __restrict__ b_inv,   // (4,1024)
    const float* __restrict__ temp,    // (1)
    const float* __restrict__ u,       // (4,N,5,8)
    const float* __restrict__ p,       // (N)
    float* __restrict__ out_q,         // (N,1024)
    float* __restrict__ out_code,      // (N,20)
    float* __restrict__ out_loss,      // (1)
    float shift012, float shift3)
{
    __shared__ float sW[11264];
    __shared__ float sLoss[4];

    const int tid  = threadIdx.x;
    const int lane = tid & 63;
    const int wib  = tid >> 6;                  // 0..3
    const int wid  = blockIdx.x * 4 + wib;
    const int row0 = wid * 2;                   // 2 rows per wave

    // ---- lane-role constants (d,c) grid; lanes 40..63 duplicate d=4 ----
    int dl = lane >> 3; if (dl > 4) dl = 4;
    const int   cl     = lane & 7;
    const float stepf  = (float)(cl - 4);
    const bool  valid  = (dl < 3) || (dl == 3 && cl >= 1 && cl <= 6)
                                  || (dl == 4 && cl >= 2 && cl <= 6);
    const float shiftd = (dl < 3) ? shift012 : ((dl == 3) ? shift3 : 0.0f);
    const float halfld = (dl < 3) ? 3.4965f : ((dl == 3) ? 2.4975f : 1.998f);
    const float offd   = (dl == 4) ? 0.0f : 0.5f;
    const float invhwd = (dl < 3) ? 0.25f : ((dl == 3) ? (1.0f/3.0f) : 0.5f);
    const int   ulane  = (lane < 40) ? lane : 39;

    const float tval = temp[0];
    const float te = fmaxf(tval * tval, 1e-8f);       // temp_eff
    const float inv_te  = 1.0f / te;                  // == alpha
    const float alpham1 = inv_te - 1.0f;

    // ---- preload ALL stages' gumbel uniforms (8 regs) + rows + p ----
    float uu[KST][2];
    #pragma unroll
    for (int i = 0; i < KST; ++i)
        #pragma unroll
        for (int rr = 0; rr < 2; ++rr)
            uu[i][rr] = u[(size_t)i * 2621440 + (size_t)(row0 + rr) * 40 + ulane];

    float4 r4[2][4];
    float  p_r[2];
    float  ss[2];
    #pragma unroll
    for (int rr = 0; rr < 2; ++rr) {
        const float4* src = (const float4*)(h_in + (size_t)(row0 + rr) * EDIM);
        #pragma unroll
        for (int j = 0; j < 4; ++j) r4[rr][j] = src[lane + 64 * j];
        p_r[rr] = p[row0 + rr];
        float s = 0.f;
        #pragma unroll
        for (int j = 0; j < 4; ++j) {
            s = fmaf(r4[rr][j].x, r4[rr][j].x, s);
            s = fmaf(r4[rr][j].y, r4[rr][j].y, s);
            s = fmaf(r4[rr][j].z, r4[rr][j].z, s);
            s = fmaf(r4[rr][j].w, r4[rr][j].w, s);
        }
        ss[rr] = (p_r[rr] <= 0.0f) ? s : 0.0f;   // p==0 edge: q_mix=0 -> ||h_in||
    }

    for (int i = 0; i < KST; ++i) {
        __syncthreads();   // protect LDS from previous stage's readers
        // ---- stage weights into LDS: 11 coalesced float4 copies/thread ----
        {
            const float4* gp = (const float4*)(W_proj + (size_t)i * 5120);
            float4* sp = (float4*)sW;
            #pragma unroll
            for (int k = 0; k < 5; ++k) sp[tid + k * 256] = gp[tid + k * 256];
            const float4* gw = (const float4*)(WiT + (size_t)i * 5120);
            float4* sw2 = (float4*)(sW + 5120);
            #pragma unroll
            for (int k = 0; k < 5; ++k) sw2[tid + k * 256] = gw[tid + k * 256];
            ((float4*)(sW + 10240))[tid] =
                ((const float4*)(b_inv + (size_t)i * EDIM))[tid];
        }
        __syncthreads();

        // ---- proj: h[d] = sum_e Wp[d][e] * r[e]; butterfly per d ----
        float hd[5][2];
        #pragma unroll
        for (int d = 0; d < 5; ++d) {
            const float bp = b_proj[i * 5 + d];
            float a0 = 0.f, a1 = 0.f;
            #pragma unroll
            for (int j = 0; j < 4; ++j) {
                const float4 w = *(const float4*)&sW[d * 1024 + 4 * lane + 256 * j];
                a0 = fmaf(w.x, r4[0][j].x, a0); a0 = fmaf(w.y, r4[0][j].y, a0);
                a0 = fmaf(w.z, r4[0][j].z, a0); a0 = fmaf(w.w, r4[0][j].w, a0);
                a1 = fmaf(w.x, r4[1][j].x, a1); a1 = fmaf(w.y, r4[1][j].y, a1);
                a1 = fmaf(w.z, r4[1][j].z, a1); a1 = fmaf(w.w, r4[1][j].w, a1);
            }
            float av[2] = {a0, a1};
            #pragma unroll
            for (int rr = 0; rr < 2; ++rr) {
                float v = av[rr];
                v += __shfl_xor(v, 1);
                v += __shfl_xor(v, 2);
                v += __shfl_xor(v, 4);
                v += __shfl_xor(v, 8);
                v += __shfl_xor(v, 16);
                v += __shfl_xor(v, 32);
                hd[d][rr] = v + bp;
            }
        }

        // ---- bound + gumbel-argmax (bit-identical math/order) ----
        float zq_mine[2];
        #pragma unroll
        for (int rr = 0; rr < 2; ++rr) {
            float hsel = hd[0][rr];
            hsel = (dl == 1) ? hd[1][rr] : hsel;
            hsel = (dl == 2) ? hd[2][rr] : hsel;
            hsel = (dl == 3) ? hd[3][rr] : hsel;
            hsel = (dl == 4) ? hd[4][rr] : hsel;
            const float z  = __fsub_rn(__fmul_rn(tanhf(hsel + shiftd), halfld), offd);
            const float g1 = logf(uu[i][rr] + 1e-20f);
            const float g  = -logf(-g1 + 1e-20f);
            const float df = __fsub_rn(z, stepf);
            float d2 = __fmul_rn(df, df);
            d2 = valid ? d2 : 1e8f;
            const float d2x = fmaf(alpham1, d2, d2);
            float y   = -(d2x * inv_te) + g;
            int   idx = cl;
            #pragma unroll
            for (int m = 1; m <= 4; m <<= 1) {     // argmax in 8-lane group
                const float yo = __shfl_xor(y, m);
                const int   io = __shfl_xor(idx, m);
                const bool take = (yo > y) || (yo == y && io < idx);
                y   = take ? yo : y;
                idx = take ? io : idx;
            }
            zq_mine[rr] = (float)(idx - 4) * invhwd;
        }
        if (lane < 40 && cl == 0) {
            #pragma unroll
            for (int rr = 0; rr < 2; ++rr)
                out_code[(size_t)(row0 + rr) * 20 + i * 5 + dl] = zq_mine[rr];
        }

        // broadcast zq[d][rr] into SGPRs (readlane, imm lane) — no VGPR cost
        float zq[5][2];
        #pragma unroll
        for (int d = 0; d < 5; ++d)
            #pragma unroll
            for (int rr = 0; rr < 2; ++rr)
                zq[d][rr] = __int_as_float(
                    __builtin_amdgcn_readlane(__float_as_int(zq_mine[rr]), d * 8));

        // ---- inverse proj fused into r update (identical rounding order):
        //      t = b_inv + zq0*w0 + ... + zq4*w4 ; r -= t ----
        #pragma unroll
        for (int j = 0; j < 4; ++j) {
            const int eo = 4 * lane + 256 * j;
            const float4 b  = *(const float4*)&sW[10240 + eo];
            const float4 w0 = *(const float4*)&sW[5120 + eo];
            const float4 w1 = *(const float4*)&sW[6144 + eo];
            const float4 w2 = *(const float4*)&sW[7168 + eo];
            const float4 w3 = *(const float4*)&sW[8192 + eo];
            const float4 w4 = *(const float4*)&sW[9216 + eo];
            #pragma unroll
            for (int rr = 0; rr < 2; ++rr) {
                float tx = b.x, ty = b.y, tz = b.z, tw = b.w;
                tx = fmaf(zq[0][rr], w0.x, tx); ty = fmaf(zq[0][rr], w0.y, ty);
                tz = fmaf(zq[0][rr], w0.z, tz); tw = fmaf(zq[0][rr], w0.w, tw);
                tx = fmaf(zq[1][rr], w1.x, tx); ty = fmaf(zq[1][rr], w1.y, ty);
                tz = fmaf(zq[1][rr], w1.z, tz); tw = fmaf(zq[1][rr], w1.w, tw);
                tx = fmaf(zq[2][rr], w2.x, tx); ty = fmaf(zq[2][rr], w2.y, ty);
                tz = fmaf(zq[2][rr], w2.z, tz); tw = fmaf(zq[2][rr], w2.w, tw);
                tx = fmaf(zq[3][rr], w3.x, tx); ty = fmaf(zq[3][rr], w3.y, ty);
                tz = fmaf(zq[3][rr], w3.z, tz); tw = fmaf(zq[3][rr], w3.w, tw);
                tx = fmaf(zq[4][rr], w4.x, tx); ty = fmaf(zq[4][rr], w4.y, ty);
                tz = fmaf(zq[4][rr], w4.z, tz); tw = fmaf(zq[4][rr], w4.w, tw);
                r4[rr][j].x -= tx; r4[rr][j].y -= ty;
                r4[rr][j].z -= tz; r4[rr][j].w -= tw;
            }
        }

        // ---- loss snapshot: ||r||^2 at the selected stage ----
        const float lo = i * 0.25f, hi = (i + 1) * 0.25f;
        #pragma unroll
        for (int rr = 0; rr < 2; ++rr) {
            if (lo < p_r[rr] && p_r[rr] <= hi) {
                float s = 0.f;
                #pragma unroll
                for (int j = 0; j < 4; ++j) {
                    s = fmaf(r4[rr][j].x, r4[rr][j].x, s);
                    s = fmaf(r4[rr][j].y, r4[rr][j].y, s);
                    s = fmaf(r4[rr][j].z, r4[rr][j].z, s);
                    s = fmaf(r4[rr][j].w, r4[rr][j].w, s);
                }
                ss[rr] = s;
            }
        }
    }

    // ---- epilogue: out_q = h_in - r_final; loss reduce ----
    float lsum = 0.f;
    #pragma unroll
    for (int rr = 0; rr < 2; ++rr) {
        float v = ss[rr];
        v += __shfl_xor(v, 1);
        v += __shfl_xor(v, 2);
        v += __shfl_xor(v, 4);
        v += __shfl_xor(v, 8);
        v += __shfl_xor(v, 16);
        v += __shfl_xor(v, 32);
        lsum += sqrtf(v);
    }
    #pragma unroll
    for (int rr = 0; rr < 2; ++rr) {
        const float4* src = (const float4*)(h_in + (size_t)(row0 + rr) * EDIM);
        float4* dst = (float4*)(out_q + (size_t)(row0 + rr) * EDIM);
        #pragma unroll
        for (int j = 0; j < 4; ++j) {
            const float4 h = src[lane + 64 * j];
            float4 o;
            o.x = h.x - r4[rr][j].x;
            o.y = h.y - r4[rr][j].y;
            o.z = h.z - r4[rr][j].z;
            o.w = h.w - r4[rr][j].w;
            dst[lane + 64 * j] = o;
        }
    }
    if (lane == 0) sLoss[wib] = lsum;
    __syncthreads();
    if (tid == 0) {
        const float bl = (sLoss[0] + sLoss[1]) + (sLoss[2] + sLoss[3]);
        atomicAdd(out_loss, bl * (1.0f / 65536.0f));
    }
}

extern "C" void kernel_launch(void* const* d_in, const int* in_sizes, int n_in,
                              void* d_out, int out_size, void* d_ws, size_t ws_size,
                              hipStream_t stream) {
    (void)in_sizes; (void)n_in; (void)out_size; (void)ws_size;
    const float* h_in   = (const float*)d_in[0];
    const float* W_proj = (const float*)d_in[1];
    const float* b_proj = (const float*)d_in[2];
    const float* W_inv  = (const float*)d_in[3];
    const float* b_inv  = (const float*)d_in[4];
    const float* temp   = (const float*)d_in[5];
    const float* u      = (const float*)d_in[6];
    const float* p      = (const float*)d_in[7];

    float* out_q    = (float*)d_out;
    float* out_code = out_q + (size_t)NROWS * EDIM;
    float* out_loss = out_code + (size_t)NROWS * 20;

    float* WiT = (float*)d_ws;   // 4*5*1024 floats = 80 KB scratch

    // loss accumulator must start at 0 (d_out is poisoned before every call)
    hipMemsetAsync(out_loss, 0, sizeof(float), stream);

    // transpose W_inv once per call (80 KB, ~2 us)
    hipLaunchKernelGGL(winv_transpose, dim3(16), dim3(256), 0, stream, W_inv, WiT);

    // shift constants computed exactly as numpy does (f64 then cast)
    double hl01 = (8.0 - 1.0) * (1.0 - 1e-3) / 2.0;   // 3.4965
    double hl3  = (6.0 - 1.0) * (1.0 - 1e-3) / 2.0;   // 2.4975
    float shift012 = (float)std::tan(0.5 / hl01);
    float shift3   = (float)std::tan(0.5 / hl3);

    dim3 grid(NROWS / 8);   // 4 waves/block * 2 rows/wave
    dim3 block(256);
    hipLaunchKernelGGL(rvq_fused, grid, block, 0, stream,
                       h_in, W_proj, b_proj, WiT, b_inv, temp, u, p,
                       out_q, out_code, out_loss, shift012, shift3);
}